// Round 1
// baseline (404.752 us; speedup 1.0000x reference)
//
#include <hip/hip_runtime.h>
#include <cmath>

#define Bn 64
#define Tn 512
#define Ln 48
#define START_L 46
#define PAD_L 45
#define END_L 47

__global__ void zero_out_k(float* __restrict__ out) {
    if (threadIdx.x == 0) out[0] = 0.0f;
}

// Gold-path energy: tg_energy = B*trans[0][START] + sum_{b,t} mask*(scores[b,t,0] + trans[0][gold[b,t]])
// Adds -tg_energy/B into out.
__global__ void tg_energy_k(const float* __restrict__ scores,
                            const int* __restrict__ gold,
                            const int* __restrict__ mask,
                            const float* __restrict__ trans,
                            float* __restrict__ out) {
    const int N = Bn * Tn;
    int idx = blockIdx.x * blockDim.x + threadIdx.x;
    float v = 0.0f;
    for (int i = idx; i < N; i += gridDim.x * blockDim.x) {
        if (mask[i]) {
            int g = gold[i];                      // in [0, L)
            v += scores[(size_t)i * Ln] + trans[g];  // trans row 0
        }
    }
    // wave reduce (64 lanes)
    #pragma unroll
    for (int off = 32; off > 0; off >>= 1) v += __shfl_down(v, off);
    __shared__ float red[8];
    int wave = threadIdx.x >> 6;
    if ((threadIdx.x & 63) == 0) red[wave] = v;
    __syncthreads();
    if (threadIdx.x == 0) {
        float s = 0.0f;
        int nw = blockDim.x >> 6;
        for (int w = 0; w < nw; ++w) s += red[w];
        atomicAdd(out, -s * (1.0f / Bn));
    }
    if (blockIdx.x == 0 && threadIdx.x == 0) {
        // the t=0 term: B * trans[0][START] / B
        atomicAdd(out, -trans[START_L]);
    }
}

// Forward scan: one block per batch element, one wave (64 threads), lane j owns label j.
__global__ __launch_bounds__(64, 1) void crf_forward_k(
        const float* __restrict__ scores,
        const int* __restrict__ mask,
        const float* __restrict__ trans,
        float* __restrict__ out) {
    const int b = blockIdx.x;
    const int lane = threadIdx.x;

    __shared__ float p_lds[2][64];

    // E column j in registers: Ecol[i] = exp(trans[i][j])
    const int jc = (lane < Ln) ? lane : (Ln - 1);
    float Ecol[Ln];
    #pragma unroll
    for (int i = 0; i < Ln; ++i) Ecol[i] = __expf(trans[i * Ln + jc]);

    // init: fs[j] = trans[START][j]   (true fs = fs_rel + C)
    float fs = (lane < Ln) ? trans[START_L * Ln + lane] : 0.0f;
    float C = 0.0f;

    const float* sb = scores + (size_t)b * Tn * Ln;
    const int*   mb = mask + (size_t)b * Tn;

    // distance-4 prefetch pipeline for scores/mask
    float scp[4];
    int   mp[4];
    #pragma unroll
    for (int k = 0; k < 4; ++k) {
        scp[k] = (lane < Ln) ? sb[k * Ln + lane] : 0.0f;
        mp[k]  = mb[k];
    }

    for (int t = 0; t < Tn; ++t) {
        const float sc = scp[t & 3];
        const int   m  = mp[t & 3];
        const int tn = t + 4;
        if (tn < Tn) {
            scp[t & 3] = (lane < Ln) ? sb[tn * Ln + lane] : 0.0f;
            mp[t & 3]  = mb[tn];
        }

        const float M = __shfl(fs, 0);   // normalizer: lane-0's fs (bounded spread)
        const float p = (lane < Ln) ? __expf(fs - M + sc) : 0.0f;
        p_lds[t & 1][lane] = p;
        __syncthreads();

        const float* pp = p_lds[t & 1];
        float a0 = 0.0f, a1 = 0.0f, a2 = 0.0f, a3 = 0.0f;
        #pragma unroll
        for (int i = 0; i < Ln; i += 4) {
            const float4 pv = *(const float4*)(pp + i);  // broadcast read
            a0 = fmaf(pv.x, Ecol[i + 0], a0);
            a1 = fmaf(pv.y, Ecol[i + 1], a1);
            a2 = fmaf(pv.z, Ecol[i + 2], a2);
            a3 = fmaf(pv.w, Ecol[i + 3], a3);
        }
        const float dot = (a0 + a1) + (a2 + a3);

        if (m) {                 // mask is uniform per (b,t) across lanes
            fs = __logf(dot);    // dot==0 -> -inf (START column), correct
            C += M;
        }
    }

    if (lane == END_L) {
        atomicAdd(out, (fs + C) * (1.0f / Bn));
    }
}

extern "C" void kernel_launch(void* const* d_in, const int* in_sizes, int n_in,
                              void* d_out, int out_size, void* d_ws, size_t ws_size,
                              hipStream_t stream) {
    const float* scores = (const float*)d_in[0];
    const int*   gold   = (const int*)d_in[1];
    const int*   mask   = (const int*)d_in[2];
    const float* trans  = (const float*)d_in[3];
    float* out = (float*)d_out;

    zero_out_k<<<1, 64, 0, stream>>>(out);
    tg_energy_k<<<64, 256, 0, stream>>>(scores, gold, mask, trans, out);
    crf_forward_k<<<Bn, 64, 0, stream>>>(scores, mask, trans, out);
}